// Round 14
// baseline (221.973 us; speedup 1.0000x reference)
//
#include <hip/hip_runtime.h>

typedef __attribute__((ext_vector_type(8))) short short8v;
typedef __attribute__((ext_vector_type(4))) float f32x4;

#define NN 40000
#define FF 512
#define HH 256
#define EE 320000
#define NHEADS 8
#define NEG_SLOPE 0.01f
#define NB 157   // ceil(NN/256)

__device__ __forceinline__ short f2bf(float x) {
    unsigned u = __float_as_uint(x);
    u += 0x7fffu + ((u >> 16) & 1u);
    return (short)(u >> 16);
}
__device__ __forceinline__ float bf2f(unsigned short b) {
    return __uint_as_float(((unsigned)b) << 16);
}

// ------- prep: W transpose->bf16 (blocks 0..511) + degree count (blocks 512..) -------
__global__ void prep_kernel(const float* __restrict__ W, short* __restrict__ Wt,
                            const int* __restrict__ src, int* __restrict__ deg) {
    int b = blockIdx.x;
    if (b < 512) {
        int i = b * 256 + threadIdx.x;     // i < 512*256
        int k = i >> 8, n = i & 255;
        float w = __builtin_nontemporal_load(&W[i]);   // read-once stream
        Wt[n * 512 + k] = f2bf(w);
    } else {
        int e = (b - 512) * 256 + threadIdx.x;
        if (e < EE) {
            int s = __builtin_nontemporal_load(&src[e]);
            atomicAdd(&deg[s], 1);
        }
    }
}

// ------- GEMM h2 = bf16(feats @ W + b) (fused f32->bf16 A-cvt) -------
__global__ __launch_bounds__(512) void gemm_kernel(
    const float* __restrict__ feats, // 40000 x 512 f32
    const short* __restrict__ Btf,   // 256 x 512 bf16 (n-major)
    const float* __restrict__ bias,  // 256
    unsigned short* __restrict__ h2) // 40000 x 256 bf16
{
    __shared__ short8v ldsA[512];    // 8 KB
    __shared__ short8v ldsB[2048];   // 32 KB
    const int tid = threadIdx.x;
    const int lane = tid & 63, w = tid >> 6;
    const int wm = w >> 2, wn = w & 3;          // 2 x 4 wave grid
    const int r0 = blockIdx.x * 64;

    const int arow = tid >> 3, aslot = tid & 7;

    f32x4 regA[2];
    short8v regB[4];

    auto stage_loadA = [&](int k0) {
        const float* p = feats + (size_t)(r0 + arow) * 512 + k0 + aslot * 8;
        // nontemporal: feats is read exactly once; keep L2 for Btf/h2
        regA[0] = __builtin_nontemporal_load(reinterpret_cast<const f32x4*>(p));
        regA[1] = __builtin_nontemporal_load(reinterpret_cast<const f32x4*>(p + 4));
    };
    auto stage_loadB = [&](int k0) {
        #pragma unroll
        for (int c = 0; c < 4; ++c) {
            int u = tid + c * 512;
            int row = u >> 3, slot = u & 7;
            regB[c] = *reinterpret_cast<const short8v*>(Btf + (size_t)row * 512 + k0 + slot * 8);
        }
    };
    auto stage_store = [&]() {
        short8v v;
        #pragma unroll
        for (int j = 0; j < 4; ++j) {
            v[j]     = f2bf(regA[0][j]);
            v[4 + j] = f2bf(regA[1][j]);
        }
        ldsA[arow * 8 + (aslot ^ (arow & 7))] = v;
        #pragma unroll
        for (int c = 0; c < 4; ++c) {
            int u = tid + c * 512;
            int row = u >> 3, slot = u & 7;
            ldsB[row * 8 + (slot ^ (row & 7))] = regB[c];
        }
    };

    f32x4 acc[2][4];
    #pragma unroll
    for (int i = 0; i < 2; ++i)
        #pragma unroll
        for (int j = 0; j < 4; ++j)
            acc[i][j] = {0.f, 0.f, 0.f, 0.f};

    stage_loadA(0);
    stage_loadB(0);

    for (int kt = 0; kt < 8; ++kt) {
        __syncthreads();
        stage_store();
        __syncthreads();
        if (kt < 7) {
            stage_loadA((kt + 1) * 64);
            stage_loadB((kt + 1) * 64);
        }
        #pragma unroll
        for (int kc = 0; kc < 2; ++kc) {
            short8v af[2], bfr[4];
            int kslot = kc * 4 + (lane >> 4);
            #pragma unroll
            for (int mr = 0; mr < 2; ++mr) {
                int row = wm * 32 + mr * 16 + (lane & 15);
                af[mr] = ldsA[row * 8 + (kslot ^ (row & 7))];
            }
            #pragma unroll
            for (int nr = 0; nr < 4; ++nr) {
                int col = wn * 64 + nr * 16 + (lane & 15);
                bfr[nr] = ldsB[col * 8 + (kslot ^ (col & 7))];
            }
            #pragma unroll
            for (int mr = 0; mr < 2; ++mr)
                #pragma unroll
                for (int nr = 0; nr < 4; ++nr)
                    acc[mr][nr] = __builtin_amdgcn_mfma_f32_16x16x32_bf16(
                        af[mr], bfr[nr], acc[mr][nr], 0, 0, 0);
        }
    }

    #pragma unroll
    for (int mr = 0; mr < 2; ++mr) {
        #pragma unroll
        for (int nr = 0; nr < 4; ++nr) {
            int gc = wn * 64 + nr * 16 + (lane & 15);
            float b = bias[gc];
            #pragma unroll
            for (int j = 0; j < 4; ++j) {
                int gr = r0 + wm * 32 + mr * 16 + (lane >> 4) * 4 + j;
                h2[(size_t)gr * 256 + gc] = (unsigned short)f2bf(acc[mr][nr][j] + b);
            }
        }
    }
}

// ------- per-node attention projections (s_src has attn_b pre-folded) -------
__global__ __launch_bounds__(256) void sproj_kernel(
    const unsigned short* __restrict__ h2, const float* __restrict__ attn_w,
    const float* __restrict__ attn_b,
    float* __restrict__ s_src, float* __restrict__ s_dst)
{
    int wid = threadIdx.x >> 6, lane = threadIdx.x & 63;
    int n = blockIdx.x * 4 + wid;
    if (n >= NN) return;
    ushort4 hb = *reinterpret_cast<const ushort4*>(h2 + (size_t)n * 256 + lane * 4);
    float4 hv = {bf2f(hb.x), bf2f(hb.y), bf2f(hb.z), bf2f(hb.w)};

    float ss[8], sd[8];
    #pragma unroll
    for (int q = 0; q < 8; ++q) {
        float4 as = *reinterpret_cast<const float4*>(attn_w + q * 512 + lane * 4);
        float4 ad = *reinterpret_cast<const float4*>(attn_w + q * 512 + 256 + lane * 4);
        ss[q] = hv.x * as.x + hv.y * as.y + hv.z * as.z + hv.w * as.w;
        sd[q] = hv.x * ad.x + hv.y * ad.y + hv.z * ad.z + hv.w * ad.w;
    }
    #pragma unroll
    for (int q = 0; q < 8; ++q) {
        #pragma unroll
        for (int off = 32; off >= 1; off >>= 1) {
            ss[q] += __shfl_xor(ss[q], off);
            sd[q] += __shfl_xor(sd[q], off);
        }
    }
    if (lane == 0) {
        #pragma unroll
        for (int q = 0; q < 8; ++q) {
            s_src[(size_t)n * 8 + q] = ss[q] + attn_b[q];   // bias folded here
            s_dst[(size_t)n * 8 + q] = sd[q];
        }
    }
}

// ---------------- scan1: per-chunk exclusive scan + chunk totals ----------------
__global__ __launch_bounds__(256) void scan1_kernel(const int* __restrict__ deg,
                                                    int* __restrict__ rowtmp,
                                                    int* __restrict__ partials)
{
    __shared__ int buf[256];
    int tid = threadIdx.x;
    int i = blockIdx.x * 256 + tid;
    int v = (i < NN) ? deg[i] : 0;
    buf[tid] = v;
    __syncthreads();
    #pragma unroll
    for (int off = 1; off < 256; off <<= 1) {
        int t = (tid >= off) ? buf[tid - off] : 0;
        __syncthreads();
        buf[tid] += t;
        __syncthreads();
    }
    if (i < NN) rowtmp[i] = buf[tid] - v;       // exclusive within block
    if (tid == 255) partials[blockIdx.x] = buf[255];
}

// ------- fused: redundant partials scan + rowstart materialize + CSR fill -------
__global__ __launch_bounds__(256) void fillrs_kernel(
    const int* __restrict__ src, const int* __restrict__ dst,
    const int* __restrict__ rowtmp, const int* __restrict__ partials,
    int* __restrict__ rowstart, int* __restrict__ cursor, int* __restrict__ csrDst)
{
    __shared__ int buf[256];
    __shared__ int offs[256];
    const int tid = threadIdx.x;
    // every block: exclusive-scan the NB partials into offs
    int v = (tid < NB) ? partials[tid] : 0;
    buf[tid] = v;
    __syncthreads();
    #pragma unroll
    for (int off = 1; off < 256; off <<= 1) {
        int t = (tid >= off) ? buf[tid - off] : 0;
        __syncthreads();
        buf[tid] += t;
        __syncthreads();
    }
    offs[tid] = buf[tid] - v;
    __syncthreads();

    // first NB blocks also materialize rowstart for agg
    if (blockIdx.x < NB) {
        int i = blockIdx.x * 256 + tid;
        if (i < NN) rowstart[i] = rowtmp[i] + offs[blockIdx.x];
        if (blockIdx.x == 0 && tid == 0) rowstart[NN] = EE;
    }

    // all blocks: CSR fill with on-the-fly rowstart
    int e = blockIdx.x * 256 + tid;
    if (e < EE) {
        int s = __builtin_nontemporal_load(&src[e]);   // read-once streams
        int d = __builtin_nontemporal_load(&dst[e]);
        int pos = atomicAdd(&cursor[s], 1);
        csrDst[rowtmp[s] + offs[s >> 8] + pos] = d;
    }
}

// ------- single-pass: inline scores + softmax + aggregation (wave per node) -------
__global__ __launch_bounds__(256) void agg_kernel(
    const unsigned short* __restrict__ h2,
    const float* __restrict__ s_src, const float* __restrict__ s_dst,
    const int* __restrict__ csrDst, const int* __restrict__ rowstart,
    float* __restrict__ out)
{
    int wid = threadIdx.x >> 6, lane = threadIdx.x & 63;
    int n = blockIdx.x * 4 + wid;
    if (n >= NN) return;
    int start = rowstart[n];
    int deg = rowstart[n + 1] - start;
    int ei = lane >> 3, hh = lane & 7;

    float ssrc = s_src[(size_t)n * 8 + hh];     // attn_b already folded

    ushort4 sb = *reinterpret_cast<const ushort4*>(h2 + (size_t)n * 256 + lane * 4);
    f32x4 hv = {bf2f(sb.x), bf2f(sb.y), bf2f(sb.z), bf2f(sb.w)};
    f32x4 acc[8];
    #pragma unroll
    for (int q = 0; q < 8; ++q) acc[q] = {0.f, 0.f, 0.f, 0.f};
    float den = 0.f;

    for (int base = 0; base < deg; base += 8) {
        int idx = base + ei;
        int dd = 0; bool valid = idx < deg;
        if (valid) dd = __builtin_nontemporal_load(&csrDst[start + idx]);  // read-once stream
        float ex = 0.f;
        if (valid) {
            float sc = ssrc + s_dst[(size_t)dd * 8 + hh];
            sc = sc > 0.f ? sc : NEG_SLOPE * sc;
            ex = __expf(sc);   // scores bounded ~|7| -> f32-safe (softmax shift-invariant)
        }
        den += ex;
        int cnt = min(8, deg - base);
        for (int t = 0; t < cnt; ++t) {
            int ddt = __shfl(dd, t * 8);
            ushort4 hb = *reinterpret_cast<const ushort4*>(h2 + (size_t)ddt * 256 + lane * 4);
            f32x4 hd = {bf2f(hb.x), bf2f(hb.y), bf2f(hb.z), bf2f(hb.w)};
            #pragma unroll
            for (int q = 0; q < 8; ++q) {
                float exq = __shfl(ex, t * 8 + q);
                acc[q] += hd * exq;
            }
        }
    }

    den += __shfl_xor(den, 8);
    den += __shfl_xor(den, 16);
    den += __shfl_xor(den, 32);   // lanes with same (lane&7) hold den for that head

    float* orow = out + (size_t)n * 2048;
    #pragma unroll
    for (int q = 0; q < 8; ++q) {
        float dq = __shfl(den, q);          // lane q holds head q's denom
        float r = dq > 0.f ? 1.f / dq : 0.f;
        f32x4 o = hv + acc[q] * r;
        // nontemporal: write-once stream; keep per-XCD L2 free for h2 gathers
        __builtin_nontemporal_store(o, reinterpret_cast<f32x4*>(orow + q * 256 + lane * 4));
    }
}

extern "C" void kernel_launch(void* const* d_in, const int* in_sizes, int n_in,
                              void* d_out, int out_size, void* d_ws, size_t ws_size,
                              hipStream_t stream) {
    const float* feats  = (const float*)d_in[0];
    const int*   adj    = (const int*)d_in[2];
    const float* W_w    = (const float*)d_in[3];
    const float* W_b    = (const float*)d_in[4];
    const float* attn_w = (const float*)d_in[5];
    const float* attn_b = (const float*)d_in[6];
    float* out = (float*)d_out;
    const int* srcA = adj;
    const int* dstA = adj + EE;

    char* ws = (char*)d_ws;
    size_t off = 0;
    auto alloc = [&](size_t bytes) -> void* {
        void* p = ws + off;
        off += (bytes + 255) & ~(size_t)255;
        return p;
    };
    short* Wt            = (short*)alloc((size_t)HH * FF * 2);
    unsigned short* h2   = (unsigned short*)alloc((size_t)NN * HH * 2);
    float* s_src   = (float*)alloc((size_t)NN * 8 * 4);
    float* s_dst   = (float*)alloc((size_t)NN * 8 * 4);
    int*   deg     = (int*)alloc((size_t)NN * 4 * 2);  // deg + cursor contiguous
    int*   cursor  = deg + NN;
    int*   rowtmp  = (int*)alloc((size_t)NN * 4);
    int*   partials= (int*)alloc((size_t)256 * 4);
    int*   rowstart= (int*)alloc((size_t)(NN + 1) * 4);
    int*   csrDst  = (int*)alloc((size_t)EE * 4);

    hipMemsetAsync(deg, 0, (size_t)2 * NN * 4, stream);
    prep_kernel<<<512 + (EE + 255) / 256, 256, 0, stream>>>(W_w, Wt, srcA, deg);
    scan1_kernel<<<NB, 256, 0, stream>>>(deg, rowtmp, partials);
    fillrs_kernel<<<(EE + 255) / 256, 256, 0, stream>>>(srcA, dstA, rowtmp, partials,
                                                        rowstart, cursor, csrDst);
    gemm_kernel<<<NN / 64, 512, 0, stream>>>(feats, Wt, W_b, h2);
    sproj_kernel<<<NN / 4, 256, 0, stream>>>(h2, attn_w, attn_b, s_src, s_dst);
    agg_kernel<<<NN / 4, 256, 0, stream>>>(h2, s_src, s_dst, csrDst, rowstart, out);
}

// Round 15
// 180.576 us; speedup vs baseline: 1.2293x; 1.2293x over previous
//
#include <hip/hip_runtime.h>

typedef __attribute__((ext_vector_type(8))) short short8v;
typedef __attribute__((ext_vector_type(4))) float f32x4;

#define NN 40000
#define FF 512
#define HH 256
#define EE 320000
#define NHEADS 8
#define NEG_SLOPE 0.01f
#define NB 157   // ceil(NN/256)

__device__ __forceinline__ short f2bf(float x) {
    unsigned u = __float_as_uint(x);
    u += 0x7fffu + ((u >> 16) & 1u);
    return (short)(u >> 16);
}
__device__ __forceinline__ float bf2f(unsigned short b) {
    return __uint_as_float(((unsigned)b) << 16);
}

// ------- prep: W transpose->bf16 (blocks 0..511) + degree count (blocks 512..) -------
__global__ void prep_kernel(const float* __restrict__ W, short* __restrict__ Wt,
                            const int* __restrict__ src, int* __restrict__ deg) {
    int b = blockIdx.x;
    if (b < 512) {
        int i = b * 256 + threadIdx.x;     // i < 512*256
        int k = i >> 8, n = i & 255;
        Wt[n * 512 + k] = f2bf(W[i]);
    } else {
        int e = (b - 512) * 256 + threadIdx.x;
        if (e < EE) atomicAdd(&deg[src[e]], 1);
    }
}

// ------- GEMM h2 = bf16(feats @ W + b) (fused f32->bf16 A-cvt) -------
__global__ __launch_bounds__(512) void gemm_kernel(
    const float* __restrict__ feats, // 40000 x 512 f32
    const short* __restrict__ Btf,   // 256 x 512 bf16 (n-major)
    const float* __restrict__ bias,  // 256
    unsigned short* __restrict__ h2) // 40000 x 256 bf16
{
    __shared__ short8v ldsA[512];    // 8 KB
    __shared__ short8v ldsB[2048];   // 32 KB
    const int tid = threadIdx.x;
    const int lane = tid & 63, w = tid >> 6;
    const int wm = w >> 2, wn = w & 3;          // 2 x 4 wave grid
    const int r0 = blockIdx.x * 64;

    const int arow = tid >> 3, aslot = tid & 7;

    float4 regA[2];
    short8v regB[4];

    auto stage_loadA = [&](int k0) {
        const float* p = feats + (size_t)(r0 + arow) * 512 + k0 + aslot * 8;
        regA[0] = *reinterpret_cast<const float4*>(p);
        regA[1] = *reinterpret_cast<const float4*>(p + 4);
    };
    auto stage_loadB = [&](int k0) {
        #pragma unroll
        for (int c = 0; c < 4; ++c) {
            int u = tid + c * 512;
            int row = u >> 3, slot = u & 7;
            regB[c] = *reinterpret_cast<const short8v*>(Btf + (size_t)row * 512 + k0 + slot * 8);
        }
    };
    auto stage_store = [&]() {
        short8v v;
        #pragma unroll
        for (int j = 0; j < 4; ++j) {
            v[j]     = f2bf(regA[0][j]);
            v[4 + j] = f2bf(regA[1][j]);
        }
        ldsA[arow * 8 + (aslot ^ (arow & 7))] = v;
        #pragma unroll
        for (int c = 0; c < 4; ++c) {
            int u = tid + c * 512;
            int row = u >> 3, slot = u & 7;
            ldsB[row * 8 + (slot ^ (row & 7))] = regB[c];
        }
    };

    f32x4 acc[2][4];
    #pragma unroll
    for (int i = 0; i < 2; ++i)
        #pragma unroll
        for (int j = 0; j < 4; ++j)
            acc[i][j] = {0.f, 0.f, 0.f, 0.f};

    stage_loadA(0);
    stage_loadB(0);

    for (int kt = 0; kt < 8; ++kt) {
        __syncthreads();
        stage_store();
        __syncthreads();
        if (kt < 7) {
            stage_loadA((kt + 1) * 64);
            stage_loadB((kt + 1) * 64);
        }
        #pragma unroll
        for (int kc = 0; kc < 2; ++kc) {
            short8v af[2], bfr[4];
            int kslot = kc * 4 + (lane >> 4);
            #pragma unroll
            for (int mr = 0; mr < 2; ++mr) {
                int row = wm * 32 + mr * 16 + (lane & 15);
                af[mr] = ldsA[row * 8 + (kslot ^ (row & 7))];
            }
            #pragma unroll
            for (int nr = 0; nr < 4; ++nr) {
                int col = wn * 64 + nr * 16 + (lane & 15);
                bfr[nr] = ldsB[col * 8 + (kslot ^ (col & 7))];
            }
            #pragma unroll
            for (int mr = 0; mr < 2; ++mr)
                #pragma unroll
                for (int nr = 0; nr < 4; ++nr)
                    acc[mr][nr] = __builtin_amdgcn_mfma_f32_16x16x32_bf16(
                        af[mr], bfr[nr], acc[mr][nr], 0, 0, 0);
        }
    }

    #pragma unroll
    for (int mr = 0; mr < 2; ++mr) {
        #pragma unroll
        for (int nr = 0; nr < 4; ++nr) {
            int gc = wn * 64 + nr * 16 + (lane & 15);
            float b = bias[gc];
            #pragma unroll
            for (int j = 0; j < 4; ++j) {
                int gr = r0 + wm * 32 + mr * 16 + (lane >> 4) * 4 + j;
                h2[(size_t)gr * 256 + gc] = (unsigned short)f2bf(acc[mr][nr][j] + b);
            }
        }
    }
}

// ------- per-node attention projections (s_src has attn_b pre-folded) -------
__global__ __launch_bounds__(256) void sproj_kernel(
    const unsigned short* __restrict__ h2, const float* __restrict__ attn_w,
    const float* __restrict__ attn_b,
    float* __restrict__ s_src, float* __restrict__ s_dst)
{
    int wid = threadIdx.x >> 6, lane = threadIdx.x & 63;
    int n = blockIdx.x * 4 + wid;
    if (n >= NN) return;
    ushort4 hb = *reinterpret_cast<const ushort4*>(h2 + (size_t)n * 256 + lane * 4);
    float4 hv = {bf2f(hb.x), bf2f(hb.y), bf2f(hb.z), bf2f(hb.w)};

    float ss[8], sd[8];
    #pragma unroll
    for (int q = 0; q < 8; ++q) {
        float4 as = *reinterpret_cast<const float4*>(attn_w + q * 512 + lane * 4);
        float4 ad = *reinterpret_cast<const float4*>(attn_w + q * 512 + 256 + lane * 4);
        ss[q] = hv.x * as.x + hv.y * as.y + hv.z * as.z + hv.w * as.w;
        sd[q] = hv.x * ad.x + hv.y * ad.y + hv.z * ad.z + hv.w * ad.w;
    }
    #pragma unroll
    for (int q = 0; q < 8; ++q) {
        #pragma unroll
        for (int off = 32; off >= 1; off >>= 1) {
            ss[q] += __shfl_xor(ss[q], off);
            sd[q] += __shfl_xor(sd[q], off);
        }
    }
    if (lane == 0) {
        #pragma unroll
        for (int q = 0; q < 8; ++q) {
            s_src[(size_t)n * 8 + q] = ss[q] + attn_b[q];   // bias folded here
            s_dst[(size_t)n * 8 + q] = sd[q];
        }
    }
}

// ---------------- scan1: per-chunk exclusive scan + chunk totals ----------------
__global__ __launch_bounds__(256) void scan1_kernel(const int* __restrict__ deg,
                                                    int* __restrict__ rowtmp,
                                                    int* __restrict__ partials)
{
    __shared__ int buf[256];
    int tid = threadIdx.x;
    int i = blockIdx.x * 256 + tid;
    int v = (i < NN) ? deg[i] : 0;
    buf[tid] = v;
    __syncthreads();
    #pragma unroll
    for (int off = 1; off < 256; off <<= 1) {
        int t = (tid >= off) ? buf[tid - off] : 0;
        __syncthreads();
        buf[tid] += t;
        __syncthreads();
    }
    if (i < NN) rowtmp[i] = buf[tid] - v;       // exclusive within block
    if (tid == 255) partials[blockIdx.x] = buf[255];
}

// ------- fused: redundant partials scan + rowstart materialize + CSR fill -------
__global__ __launch_bounds__(256) void fillrs_kernel(
    const int* __restrict__ src, const int* __restrict__ dst,
    const int* __restrict__ rowtmp, const int* __restrict__ partials,
    int* __restrict__ rowstart, int* __restrict__ cursor, int* __restrict__ csrDst)
{
    __shared__ int buf[256];
    __shared__ int offs[256];
    const int tid = threadIdx.x;
    // every block: exclusive-scan the NB partials into offs
    int v = (tid < NB) ? partials[tid] : 0;
    buf[tid] = v;
    __syncthreads();
    #pragma unroll
    for (int off = 1; off < 256; off <<= 1) {
        int t = (tid >= off) ? buf[tid - off] : 0;
        __syncthreads();
        buf[tid] += t;
        __syncthreads();
    }
    offs[tid] = buf[tid] - v;
    __syncthreads();

    // first NB blocks also materialize rowstart for agg
    if (blockIdx.x < NB) {
        int i = blockIdx.x * 256 + tid;
        if (i < NN) rowstart[i] = rowtmp[i] + offs[blockIdx.x];
        if (blockIdx.x == 0 && tid == 0) rowstart[NN] = EE;
    }

    // all blocks: CSR fill with on-the-fly rowstart
    int e = blockIdx.x * 256 + tid;
    if (e < EE) {
        int s = src[e];
        int pos = atomicAdd(&cursor[s], 1);
        csrDst[rowtmp[s] + offs[s >> 8] + pos] = dst[e];
    }
}

// ------- single-pass: inline scores + softmax + aggregation (wave per node) -------
__global__ __launch_bounds__(256) void agg_kernel(
    const unsigned short* __restrict__ h2,
    const float* __restrict__ s_src, const float* __restrict__ s_dst,
    const int* __restrict__ csrDst, const int* __restrict__ rowstart,
    float* __restrict__ out)
{
    int wid = threadIdx.x >> 6, lane = threadIdx.x & 63;
    int n = blockIdx.x * 4 + wid;
    if (n >= NN) return;
    int start = rowstart[n];
    int deg = rowstart[n + 1] - start;
    int ei = lane >> 3, hh = lane & 7;

    float ssrc = s_src[(size_t)n * 8 + hh];     // attn_b already folded

    ushort4 sb = *reinterpret_cast<const ushort4*>(h2 + (size_t)n * 256 + lane * 4);
    f32x4 hv = {bf2f(sb.x), bf2f(sb.y), bf2f(sb.z), bf2f(sb.w)};
    f32x4 acc[8];
    #pragma unroll
    for (int q = 0; q < 8; ++q) acc[q] = {0.f, 0.f, 0.f, 0.f};
    float den = 0.f;

    for (int base = 0; base < deg; base += 8) {
        int idx = base + ei;
        int dd = 0; bool valid = idx < deg;
        if (valid) dd = csrDst[start + idx];    // 8 lanes per edge share dd via shfl
        float ex = 0.f;
        if (valid) {
            float sc = ssrc + s_dst[(size_t)dd * 8 + hh];
            sc = sc > 0.f ? sc : NEG_SLOPE * sc;
            ex = __expf(sc);   // scores bounded ~|7| -> f32-safe (softmax shift-invariant)
        }
        den += ex;
        int cnt = min(8, deg - base);
        for (int t = 0; t < cnt; ++t) {
            int ddt = __shfl(dd, t * 8);
            ushort4 hb = *reinterpret_cast<const ushort4*>(h2 + (size_t)ddt * 256 + lane * 4);
            f32x4 hd = {bf2f(hb.x), bf2f(hb.y), bf2f(hb.z), bf2f(hb.w)};
            #pragma unroll
            for (int q = 0; q < 8; ++q) {
                float exq = __shfl(ex, t * 8 + q);
                acc[q] += hd * exq;
            }
        }
    }

    den += __shfl_xor(den, 8);
    den += __shfl_xor(den, 16);
    den += __shfl_xor(den, 32);   // lanes with same (lane&7) hold den for that head

    float* orow = out + (size_t)n * 2048;
    #pragma unroll
    for (int q = 0; q < 8; ++q) {
        float dq = __shfl(den, q);          // lane q holds head q's denom
        float r = dq > 0.f ? 1.f / dq : 0.f;
        f32x4 o = hv + acc[q] * r;
        // nontemporal: write-once stream; keep per-XCD L2 free for h2 gathers
        __builtin_nontemporal_store(o, reinterpret_cast<f32x4*>(orow + q * 256 + lane * 4));
    }
}

extern "C" void kernel_launch(void* const* d_in, const int* in_sizes, int n_in,
                              void* d_out, int out_size, void* d_ws, size_t ws_size,
                              hipStream_t stream) {
    const float* feats  = (const float*)d_in[0];
    const int*   adj    = (const int*)d_in[2];
    const float* W_w    = (const float*)d_in[3];
    const float* W_b    = (const float*)d_in[4];
    const float* attn_w = (const float*)d_in[5];
    const float* attn_b = (const float*)d_in[6];
    float* out = (float*)d_out;
    const int* srcA = adj;
    const int* dstA = adj + EE;

    char* ws = (char*)d_ws;
    size_t off = 0;
    auto alloc = [&](size_t bytes) -> void* {
        void* p = ws + off;
        off += (bytes + 255) & ~(size_t)255;
        return p;
    };
    short* Wt            = (short*)alloc((size_t)HH * FF * 2);
    unsigned short* h2   = (unsigned short*)alloc((size_t)NN * HH * 2);
    float* s_src   = (float*)alloc((size_t)NN * 8 * 4);
    float* s_dst   = (float*)alloc((size_t)NN * 8 * 4);
    int*   deg     = (int*)alloc((size_t)NN * 4 * 2);  // deg + cursor contiguous
    int*   cursor  = deg + NN;
    int*   rowtmp  = (int*)alloc((size_t)NN * 4);
    int*   partials= (int*)alloc((size_t)256 * 4);
    int*   rowstart= (int*)alloc((size_t)(NN + 1) * 4);
    int*   csrDst  = (int*)alloc((size_t)EE * 4);

    hipMemsetAsync(deg, 0, (size_t)2 * NN * 4, stream);
    prep_kernel<<<512 + (EE + 255) / 256, 256, 0, stream>>>(W_w, Wt, srcA, deg);
    scan1_kernel<<<NB, 256, 0, stream>>>(deg, rowtmp, partials);
    fillrs_kernel<<<(EE + 255) / 256, 256, 0, stream>>>(srcA, dstA, rowtmp, partials,
                                                        rowstart, cursor, csrDst);
    gemm_kernel<<<NN / 64, 512, 0, stream>>>(feats, Wt, W_b, h2);
    sproj_kernel<<<NN / 4, 256, 0, stream>>>(h2, attn_w, attn_b, s_src, s_dst);
    agg_kernel<<<NN / 4, 256, 0, stream>>>(h2, s_src, s_dst, csrDst, rowstart, out);
}